// Round 10
// baseline (466.909 us; speedup 1.0000x reference)
//
#include <hip/hip_runtime.h>
#include <hip/hip_bf16.h>

#define NB 128
#define MT 64
#define DM 256
#define DI 512
#define DS 16
#define DR 16
#define NTOK (NB*MT)   // 8192

using bf16 = __hip_bfloat16;

__device__ __forceinline__ float B2F(bf16 v) { return __bfloat162float(v); }
__device__ __forceinline__ bf16  F2B(float f) { return __float2bfloat16(f); }

// Inputs: fp32, dict-interleaved order. Output: fp32. Internal ws: bf16 (+fp32 dbc).
// ws layout (39 MB):
//   xn   bf16 els [0, 2,097,152)
//   xs   bf16 els [2,097,152, 10,485,760)   (logical time; overwritten by gated y)
//   zb   bf16 els [10,485,760, 18,874,368)  (logical time)
//   dbc  f32  at byte 37,748,736 (786,432 floats)

__global__ void fillcode_k(float* out, int n, float code) {
    int i = blockIdx.x * 256 + threadIdx.x;
    if (i < n) out[i] = code;
}

// ---------------- LayerNorm (fp32 in, bf16 out) ----------------
__global__ __launch_bounds__(256) void ln_k(const float* __restrict__ x,
                                            const float* __restrict__ g,
                                            const float* __restrict__ bt,
                                            bf16* __restrict__ xn) {
    __shared__ float rs[256], rq[256];
    int tok = blockIdx.x, tid = threadIdx.x;
    float v = x[(size_t)tok * DM + tid];
    rs[tid] = v; rq[tid] = v * v;
    __syncthreads();
    for (int o = 128; o > 0; o >>= 1) {
        if (tid < o) { rs[tid] += rs[tid + o]; rq[tid] += rq[tid + o]; }
        __syncthreads();
    }
    float mu  = rs[0] * (1.0f / DM);
    float var = rq[0] * (1.0f / DM) - mu * mu;
    float inv = rsqrtf(fmaxf(var, 0.f) + 1e-5f);
    xn[(size_t)tok * DM + tid] = F2B((v - mu) * inv * g[tid] + bt[tid]);
}

// ---------------- in_proj GEMM + fused causal conv + SiLU ----------------
__global__ __launch_bounds__(256) void inproj_conv_k(
        const bf16* __restrict__ xn,
        const float* __restrict__ Wf, const float* __restrict__ Wb,
        const float* __restrict__ cwf, const float* __restrict__ cbf,
        const float* __restrict__ cwb, const float* __restrict__ cbb,
        bf16* __restrict__ xs, bf16* __restrict__ zb) {
    int b = blockIdx.x, n0 = blockIdx.y * 64, dir = blockIdx.z;
    const float* W = dir ? Wb : Wf;
    __shared__ float As[32][65];
    __shared__ float Bs[32][65];
    __shared__ float tile[64][65];
    int tid = threadIdx.x, tx = tid & 15, ty = tid >> 4;
    float acc[4][4] = {};
    int arow = tid >> 2, ac0 = (tid & 3) * 8;
    const bf16* Ab = xn + (size_t)b * MT * DM;
    const float* Bb = W + (size_t)n0 * DM;
    for (int k0 = 0; k0 < DM; k0 += 32) {
        #pragma unroll
        for (int q = 0; q < 8; ++q) {
            As[ac0 + q][arow] = B2F(Ab[(size_t)arow * DM + k0 + ac0 + q]);
            Bs[ac0 + q][arow] = Bb[(size_t)arow * DM + k0 + ac0 + q];
        }
        __syncthreads();
        #pragma unroll
        for (int kk = 0; kk < 32; ++kk) {
            float a[4], bb[4];
            #pragma unroll
            for (int i = 0; i < 4; ++i) a[i] = As[kk][ty * 4 + i];
            #pragma unroll
            for (int j = 0; j < 4; ++j) bb[j] = Bs[kk][tx * 4 + j];
            #pragma unroll
            for (int i = 0; i < 4; ++i)
                #pragma unroll
                for (int j = 0; j < 4; ++j) acc[i][j] = fmaf(a[i], bb[j], acc[i][j]);
        }
        __syncthreads();
    }
    size_t outbase = ((size_t)(dir * NB + b) * MT) * DI;
    if (n0 < DI) {
        #pragma unroll
        for (int i = 0; i < 4; ++i)
            #pragma unroll
            for (int j = 0; j < 4; ++j) tile[ty * 4 + i][tx * 4 + j] = acc[i][j];
        __syncthreads();
        const float* cw = dir ? cwb : cwf;
        const float* cb = dir ? cbb : cbf;
        #pragma unroll
        for (int i = 0; i < 4; ++i) {
            int l = ty * 4 + i;                     // logical time
            #pragma unroll
            for (int j = 0; j < 4; ++j) {
                int c = tx * 4 + j;
                int d = n0 + c;
                float a2 = cb[d];
                #pragma unroll
                for (int k = 0; k < 4; ++k) {
                    int jj = l - 3 + k;             // logical input time
                    if (jj >= 0) {
                        int p = dir ? (MT - 1 - jj) : jj;   // physical row
                        a2 = fmaf(tile[p][c], cw[d * 4 + k], a2);
                    }
                }
                xs[outbase + (size_t)l * DI + d] = F2B(a2 / (1.0f + __expf(-a2)));
            }
        }
    } else {
        #pragma unroll
        for (int i = 0; i < 4; ++i) {
            int p = ty * 4 + i;                     // physical time
            int l = dir ? (MT - 1 - p) : p;         // logical time
            #pragma unroll
            for (int j = 0; j < 4; ++j) {
                int d = n0 - DI + tx * 4 + j;
                zb[outbase + (size_t)l * DI + d] = F2B(acc[i][j]);
            }
        }
    }
}

// ---------------- x_proj: dbc = xs @ W^T ----------------
__global__ __launch_bounds__(256) void xproj_k(const bf16* __restrict__ xs,
                                               const float* __restrict__ Wf,
                                               const float* __restrict__ Wb,
                                               float* __restrict__ dbc) {
    const int K = DI, N = DR + 2 * DS;
    int bm = blockIdx.x;
    int dir = bm >> 7;
    const float* W = dir ? Wb : Wf;
    __shared__ float As[32][65];
    __shared__ float Bs[32][49];
    int m0 = bm * 64;
    int tid = threadIdx.x, tx = tid & 15, ty = tid >> 4;
    float acc[4][3] = {};
    int arow = tid >> 2, ac0 = (tid & 3) * 8;
    for (int k0 = 0; k0 < K; k0 += 32) {
        #pragma unroll
        for (int q = 0; q < 8; ++q)
            As[ac0 + q][arow] = B2F(xs[(size_t)(m0 + arow) * K + k0 + ac0 + q]);
        for (int idx = tid; idx < N * 32; idx += 256) {
            int r = idx >> 5, kk = idx & 31;
            Bs[kk][r] = W[(size_t)r * K + k0 + kk];
        }
        __syncthreads();
        #pragma unroll
        for (int kk = 0; kk < 32; ++kk) {
            float a[4], bb[3];
            #pragma unroll
            for (int i = 0; i < 4; ++i) a[i] = As[kk][ty * 4 + i];
            #pragma unroll
            for (int j = 0; j < 3; ++j) bb[j] = Bs[kk][tx * 3 + j];
            #pragma unroll
            for (int i = 0; i < 4; ++i)
                #pragma unroll
                for (int j = 0; j < 3; ++j) acc[i][j] = fmaf(a[i], bb[j], acc[i][j]);
        }
        __syncthreads();
    }
    #pragma unroll
    for (int i = 0; i < 4; ++i)
        #pragma unroll
        for (int j = 0; j < 3; ++j)
            dbc[(size_t)(m0 + ty * 4 + i) * N + tx * 3 + j] = acc[i][j];
}

// ---------------- fused dt_proj + softplus + selective scan + gating ----------------
__global__ __launch_bounds__(256) void scan_k(bf16* __restrict__ xs,
                                              const bf16* __restrict__ zb,
                                              const float* __restrict__ dbc,
                                              const float* __restrict__ dtwf, const float* __restrict__ dtbf,
                                              const float* __restrict__ Alf,  const float* __restrict__ Df,
                                              const float* __restrict__ dtwb, const float* __restrict__ dtbb,
                                              const float* __restrict__ Alb,  const float* __restrict__ Db) {
    int db  = blockIdx.x;      // dir*128 + b
    int dir = db >> 7;
    int tid = threadIdx.x;
    int d   = blockIdx.y * 256 + tid;
    const float* dtw = dir ? dtwb : dtwf;
    const float* dtb = dir ? dtbb : dtbf;
    const float* Al  = dir ? Alb  : Alf;
    const float* Dv  = dir ? Db   : Df;
    __shared__ float dbs[MT][48];
    const float* dbc_b = dbc + (size_t)db * MT * 48;
    for (int idx = tid; idx < MT * 48; idx += 256) dbs[idx / 48][idx % 48] = dbc_b[idx];
    __syncthreads();
    float w[DR], A[DS], h[DS];
    #pragma unroll
    for (int r = 0; r < DR; ++r) w[r] = dtw[d * DR + r];
    #pragma unroll
    for (int s = 0; s < DS; ++s) { A[s] = -__expf(Al[d * DS + s]); h[s] = 0.f; }
    float bias = dtb[d], Dd = Dv[d];
    bf16* xs_b = xs + (size_t)db * MT * DI;
    const bf16* z_b = zb + (size_t)db * MT * DI;
    for (int t = 0; t < MT; ++t) {
        float xval = B2F(xs_b[t * DI + d]);
        float pre = bias;
        #pragma unroll
        for (int r = 0; r < DR; ++r) pre = fmaf(dbs[t][r], w[r], pre);
        float dt = (pre > 15.f) ? pre : __logf(1.0f + __expf(pre));
        float y = 0.f;
        #pragma unroll
        for (int s = 0; s < DS; ++s) {
            float dA = __expf(dt * A[s]);
            h[s] = fmaf(dA, h[s], dt * dbs[t][DR + s] * xval);
            y = fmaf(h[s], dbs[t][DR + DS + s], y);
        }
        y = fmaf(xval, Dd, y);
        float zv = B2F(z_b[t * DI + d]);
        float sz = zv / (1.0f + __expf(-zv));
        xs_b[t * DI + d] = F2B(y * sz);
    }
}

// ---------------- out_proj (both dirs, flip-back) + residual (fp32 out) ----------------
__global__ __launch_bounds__(256) void out_k(const bf16* __restrict__ yg,
                                             const float* __restrict__ Wf,
                                             const float* __restrict__ Wb,
                                             const float* __restrict__ x,
                                             float* __restrict__ out) {
    int b  = blockIdx.x;
    int n0 = blockIdx.y * 64;
    __shared__ float As[32][65];
    __shared__ float Bs[32][65];
    int tid = threadIdx.x, tx = tid & 15, ty = tid >> 4;
    float acc[4][4] = {};
    int arow = tid >> 2, ac0 = (tid & 3) * 8;
    for (int dir = 0; dir < 2; ++dir) {
        const float* W  = dir ? Wb : Wf;
        const bf16* Ab  = yg + (size_t)(dir * NB + b) * MT * DI;
        const float* Bb = W + (size_t)n0 * DI;
        for (int k0 = 0; k0 < DI; k0 += 32) {
            int l = dir ? (MT - 1 - arow) : arow;   // logical row for physical arow
            #pragma unroll
            for (int q = 0; q < 8; ++q) {
                As[ac0 + q][arow] = B2F(Ab[(size_t)l * DI + k0 + ac0 + q]);
                Bs[ac0 + q][arow] = Bb[(size_t)arow * DI + k0 + ac0 + q];
            }
            __syncthreads();
            #pragma unroll
            for (int kk = 0; kk < 32; ++kk) {
                float a[4], bb[4];
                #pragma unroll
                for (int i = 0; i < 4; ++i) a[i] = As[kk][ty * 4 + i];
                #pragma unroll
                for (int j = 0; j < 4; ++j) bb[j] = Bs[kk][tx * 4 + j];
                #pragma unroll
                for (int i = 0; i < 4; ++i)
                    #pragma unroll
                    for (int j = 0; j < 4; ++j) acc[i][j] = fmaf(a[i], bb[j], acc[i][j]);
            }
            __syncthreads();
        }
    }
    #pragma unroll
    for (int i = 0; i < 4; ++i) {
        int m = ty * 4 + i;
        #pragma unroll
        for (int j = 0; j < 4; ++j) {
            size_t o = ((size_t)(b * MT + m)) * DM + n0 + tx * 4 + j;
            out[o] = acc[i][j] + x[o];
        }
    }
}

extern "C" void kernel_launch(void* const* d_in, const int* in_sizes, int n_in,
                              void* d_out, int out_size, void* d_ws, size_t ws_size,
                              hipStream_t stream) {
    float* out = (float*)d_out;
    // dict-interleaved size vector (verified matching in round 9)
    static const int dictv[21] = {2097152,256,256,262144,262144,2048,2048,512,512,24576,24576,
                                  8192,8192,512,512,8192,8192,512,512,131072,131072};
    bool ok = (n_in == 21);
    if (ok) for (int i = 0; i < 21; ++i) if (in_sizes[i] != dictv[i]) { ok = false; break; }
    if (!ok) {
        fillcode_k<<<(out_size + 255) / 256, 256, 0, stream>>>(out, out_size, 4e9f);
        return;
    }
    const float* x     = (const float*)d_in[0];
    const float* lng   = (const float*)d_in[1];
    const float* lnb   = (const float*)d_in[2];
    const float* f_inw = (const float*)d_in[3];
    const float* b_inw = (const float*)d_in[4];
    const float* f_cw  = (const float*)d_in[5];
    const float* b_cw  = (const float*)d_in[6];
    const float* f_cb  = (const float*)d_in[7];
    const float* b_cb  = (const float*)d_in[8];
    const float* f_xpw = (const float*)d_in[9];
    const float* b_xpw = (const float*)d_in[10];
    const float* f_dtw = (const float*)d_in[11];
    const float* b_dtw = (const float*)d_in[12];
    const float* f_dtb = (const float*)d_in[13];
    const float* b_dtb = (const float*)d_in[14];
    const float* f_al  = (const float*)d_in[15];
    const float* b_al  = (const float*)d_in[16];
    const float* f_d   = (const float*)d_in[17];
    const float* b_d   = (const float*)d_in[18];
    const float* f_ow  = (const float*)d_in[19];
    const float* b_ow  = (const float*)d_in[20];

    bf16* xn   = (bf16*)d_ws;
    bf16* xs   = xn + (size_t)NTOK * DM;
    bf16* zb   = xs + (size_t)2 * NTOK * DI;
    float* dbc = (float*)((char*)d_ws + 37748736ull);

    ln_k<<<NTOK, 256, 0, stream>>>(x, lng, lnb, xn);
    {
        dim3 g(NB, (2 * DI) / 64, 2);
        inproj_conv_k<<<g, 256, 0, stream>>>(xn, f_inw, b_inw,
                                             f_cw, f_cb, b_cw, b_cb, xs, zb);
    }
    xproj_k<<<(2 * NTOK) / 64, 256, 0, stream>>>(xs, f_xpw, b_xpw, dbc);
    {
        dim3 g(2 * NB, DI / 256);
        scan_k<<<g, 256, 0, stream>>>(xs, zb, dbc,
                                      f_dtw, f_dtb, f_al, f_d,
                                      b_dtw, b_dtb, b_al, b_d);
    }
    {
        dim3 g(NB, DM / 64);
        out_k<<<g, 256, 0, stream>>>(xs, f_ow, b_ow, x, out);
    }
}

// Round 11
// 298.151 us; speedup vs baseline: 1.5660x; 1.5660x over previous
//
#include <hip/hip_runtime.h>
#include <hip/hip_bf16.h>

#define NB 128
#define MT 64
#define DM 256
#define DI 512
#define DS 16
#define DR 16
#define NTOK (NB*MT)   // 8192

using bf16 = __hip_bfloat16;
typedef unsigned short u16;
typedef __attribute__((ext_vector_type(8))) short short8;
typedef __attribute__((ext_vector_type(4))) float f32x4;

__device__ __forceinline__ float B2F(bf16 v) { return __bfloat162float(v); }
__device__ __forceinline__ bf16  F2B(float f) { return __float2bfloat16(f); }
__device__ __forceinline__ unsigned pack2bf(float lo, float hi) {
    unsigned a = __float_as_uint(lo), b = __float_as_uint(hi);
    a = (a + 0x7FFFu + ((a >> 16) & 1u)) >> 16;
    b = (b + 0x7FFFu + ((b >> 16) & 1u)) >> 16;
    return a | (b << 16);
}

// Inputs: fp32, dict-interleaved order. Output: fp32. Internal ws: bf16 (+fp32 dbc).
// ws layout (39 MB):
//   xn   bf16 els [0, 2,097,152)
//   xs   bf16 els [2,097,152, 10,485,760)   (logical time; overwritten by gated y)
//   zb   bf16 els [10,485,760, 18,874,368)  (logical time)
//   dbc  f32  at byte 37,748,736 (786,432 floats)

__global__ void fillcode_k(float* out, int n, float code) {
    int i = blockIdx.x * 256 + threadIdx.x;
    if (i < n) out[i] = code;
}

// ---------------- LayerNorm (fp32 in, bf16 out) ----------------
__global__ __launch_bounds__(256) void ln_k(const float* __restrict__ x,
                                            const float* __restrict__ g,
                                            const float* __restrict__ bt,
                                            bf16* __restrict__ xn) {
    __shared__ float rs[256], rq[256];
    int tok = blockIdx.x, tid = threadIdx.x;
    float v = x[(size_t)tok * DM + tid];
    rs[tid] = v; rq[tid] = v * v;
    __syncthreads();
    for (int o = 128; o > 0; o >>= 1) {
        if (tid < o) { rs[tid] += rs[tid + o]; rq[tid] += rq[tid + o]; }
        __syncthreads();
    }
    float mu  = rs[0] * (1.0f / DM);
    float var = rq[0] * (1.0f / DM) - mu * mu;
    float inv = rsqrtf(fmaxf(var, 0.f) + 1e-5f);
    xn[(size_t)tok * DM + tid] = F2B((v - mu) * inv * g[tid] + bt[tid]);
}

// ---------------- in_proj MFMA GEMM + fused causal conv + SiLU ----------------
// block: 64(time) x 64(channel) C-tile; 4 waves, each 16 rows x 64 cols.
// A = xn (bf16), B = W row-major fp32 -> bf16 staged. K=256, BK=64.
__global__ __launch_bounds__(256) void inproj_conv_mfma(
        const bf16* __restrict__ xn,
        const float* __restrict__ Wf, const float* __restrict__ Wb,
        const float* __restrict__ cwf, const float* __restrict__ cbf,
        const float* __restrict__ cwb, const float* __restrict__ cbb,
        bf16* __restrict__ xs, bf16* __restrict__ zb) {
    int b = blockIdx.x, n0 = blockIdx.y * 64, dir = blockIdx.z;
    const float* W = dir ? Wb : Wf;
    __shared__ __align__(16) char smem[18432];
    u16* A_lds = (u16*)smem;              // [64][72] bf16
    u16* B_lds = (u16*)(smem + 9216);     // [64][72] bf16
    float* tile = (float*)smem;           // [64][65] fp32 (aliased after K-loop)
    int tid = threadIdx.x;
    int lane = tid & 63, wave = tid >> 6;
    int m_rel = lane & 15, quad = lane >> 4;
    int wrow0 = wave * 16;
    f32x4 acc[4];
    #pragma unroll
    for (int nt = 0; nt < 4; ++nt) acc[nt] = (f32x4){0.f, 0.f, 0.f, 0.f};

    int sr = tid >> 2;            // staging row 0..63
    int sc = (tid & 3) * 16;      // staging col 0,16,32,48
    const u16* Ab = (const u16*)(xn + (size_t)b * MT * DM);
    for (int k0 = 0; k0 < DM; k0 += 64) {
        // stage A (bf16 copy)
        const uint4* asrc = (const uint4*)(Ab + (size_t)sr * DM + k0 + sc);
        uint4* adst = (uint4*)(A_lds + sr * 72 + sc);
        adst[0] = asrc[0]; adst[1] = asrc[1];
        // stage B (fp32 -> bf16)
        const float4* bsrc = (const float4*)(W + (size_t)(n0 + sr) * DM + k0 + sc);
        float4 b0 = bsrc[0], b1 = bsrc[1], b2 = bsrc[2], b3 = bsrc[3];
        uint4 p0 = { pack2bf(b0.x,b0.y), pack2bf(b0.z,b0.w), pack2bf(b1.x,b1.y), pack2bf(b1.z,b1.w) };
        uint4 p1 = { pack2bf(b2.x,b2.y), pack2bf(b2.z,b2.w), pack2bf(b3.x,b3.y), pack2bf(b3.z,b3.w) };
        uint4* bdst = (uint4*)(B_lds + sr * 72 + sc);
        bdst[0] = p0; bdst[1] = p1;
        __syncthreads();
        #pragma unroll
        for (int ks = 0; ks < 64; ks += 32) {
            short8 a = *(const short8*)(A_lds + (wrow0 + m_rel) * 72 + ks + quad * 8);
            #pragma unroll
            for (int nt = 0; nt < 4; ++nt) {
                short8 bf = *(const short8*)(B_lds + (nt * 16 + m_rel) * 72 + ks + quad * 8);
                acc[nt] = __builtin_amdgcn_mfma_f32_16x16x32_bf16(a, bf, acc[nt], 0, 0, 0);
            }
        }
        __syncthreads();
    }
    // D -> tile:  D[m = wrow0+quad*4+reg][n = nt*16+m_rel]
    #pragma unroll
    for (int nt = 0; nt < 4; ++nt)
        #pragma unroll
        for (int r = 0; r < 4; ++r)
            tile[(wrow0 + quad * 4 + r) * 65 + nt * 16 + m_rel] = acc[nt][r];
    __syncthreads();

    // epilogue (identical semantics to verified round-10 kernel)
    int tx = tid & 15, ty = tid >> 4;
    size_t outbase = ((size_t)(dir * NB + b) * MT) * DI;
    if (n0 < DI) {
        const float* cw = dir ? cwb : cwf;
        const float* cb = dir ? cbb : cbf;
        #pragma unroll
        for (int i = 0; i < 4; ++i) {
            int l = ty * 4 + i;                     // logical time
            #pragma unroll
            for (int j = 0; j < 4; ++j) {
                int c = tx * 4 + j;
                int d = n0 + c;
                float a2 = cb[d];
                #pragma unroll
                for (int k = 0; k < 4; ++k) {
                    int jj = l - 3 + k;             // logical input time
                    if (jj >= 0) {
                        int p = dir ? (MT - 1 - jj) : jj;   // physical row
                        a2 = fmaf(tile[p * 65 + c], cw[d * 4 + k], a2);
                    }
                }
                xs[outbase + (size_t)l * DI + d] = F2B(a2 / (1.0f + __expf(-a2)));
            }
        }
    } else {
        #pragma unroll
        for (int i = 0; i < 4; ++i) {
            int p = ty * 4 + i;                     // physical time
            int l = dir ? (MT - 1 - p) : p;         // logical time
            #pragma unroll
            for (int j = 0; j < 4; ++j) {
                int c = tx * 4 + j;
                int d = n0 - DI + c;
                zb[outbase + (size_t)l * DI + d] = F2B(tile[p * 65 + c]);
            }
        }
    }
}

// ---------------- x_proj: dbc = xs @ W^T (fp32 VALU, small) ----------------
__global__ __launch_bounds__(256) void xproj_k(const bf16* __restrict__ xs,
                                               const float* __restrict__ Wf,
                                               const float* __restrict__ Wb,
                                               float* __restrict__ dbc) {
    const int K = DI, N = DR + 2 * DS;
    int bm = blockIdx.x;
    int dir = bm >> 7;
    const float* W = dir ? Wb : Wf;
    __shared__ float As[32][65];
    __shared__ float Bs[32][49];
    int m0 = bm * 64;
    int tid = threadIdx.x, tx = tid & 15, ty = tid >> 4;
    float acc[4][3] = {};
    int arow = tid >> 2, ac0 = (tid & 3) * 8;
    for (int k0 = 0; k0 < K; k0 += 32) {
        #pragma unroll
        for (int q = 0; q < 8; ++q)
            As[ac0 + q][arow] = B2F(xs[(size_t)(m0 + arow) * K + k0 + ac0 + q]);
        for (int idx = tid; idx < N * 32; idx += 256) {
            int r = idx >> 5, kk = idx & 31;
            Bs[kk][r] = W[(size_t)r * K + k0 + kk];
        }
        __syncthreads();
        #pragma unroll
        for (int kk = 0; kk < 32; ++kk) {
            float a[4], bb[3];
            #pragma unroll
            for (int i = 0; i < 4; ++i) a[i] = As[kk][ty * 4 + i];
            #pragma unroll
            for (int j = 0; j < 3; ++j) bb[j] = Bs[kk][tx * 3 + j];
            #pragma unroll
            for (int i = 0; i < 4; ++i)
                #pragma unroll
                for (int j = 0; j < 3; ++j) acc[i][j] = fmaf(a[i], bb[j], acc[i][j]);
        }
        __syncthreads();
    }
    #pragma unroll
    for (int i = 0; i < 4; ++i)
        #pragma unroll
        for (int j = 0; j < 3; ++j)
            dbc[(size_t)(m0 + ty * 4 + i) * N + tx * 3 + j] = acc[i][j];
}

// ---------------- fused dt_proj + softplus + selective scan + gating ----------------
__global__ __launch_bounds__(256) void scan_k(bf16* __restrict__ xs,
                                              const bf16* __restrict__ zb,
                                              const float* __restrict__ dbc,
                                              const float* __restrict__ dtwf, const float* __restrict__ dtbf,
                                              const float* __restrict__ Alf,  const float* __restrict__ Df,
                                              const float* __restrict__ dtwb, const float* __restrict__ dtbb,
                                              const float* __restrict__ Alb,  const float* __restrict__ Db) {
    int db  = blockIdx.x;      // dir*128 + b
    int dir = db >> 7;
    int tid = threadIdx.x;
    int d   = blockIdx.y * 256 + tid;
    const float* dtw = dir ? dtwb : dtwf;
    const float* dtb = dir ? dtbb : dtbf;
    const float* Al  = dir ? Alb  : Alf;
    const float* Dv  = dir ? Db   : Df;
    __shared__ float dbs[MT][48];
    const float* dbc_b = dbc + (size_t)db * MT * 48;
    for (int idx = tid; idx < MT * 48; idx += 256) dbs[idx / 48][idx % 48] = dbc_b[idx];
    __syncthreads();
    float w[DR], A[DS], h[DS];
    #pragma unroll
    for (int r = 0; r < DR; ++r) w[r] = dtw[d * DR + r];
    #pragma unroll
    for (int s = 0; s < DS; ++s) { A[s] = -__expf(Al[d * DS + s]); h[s] = 0.f; }
    float bias = dtb[d], Dd = Dv[d];
    bf16* xs_b = xs + (size_t)db * MT * DI;
    const bf16* z_b = zb + (size_t)db * MT * DI;
    for (int t = 0; t < MT; ++t) {
        float xval = B2F(xs_b[t * DI + d]);
        float pre = bias;
        #pragma unroll
        for (int r = 0; r < DR; ++r) pre = fmaf(dbs[t][r], w[r], pre);
        float dt = (pre > 15.f) ? pre : __logf(1.0f + __expf(pre));
        float y = 0.f;
        #pragma unroll
        for (int s = 0; s < DS; ++s) {
            float dA = __expf(dt * A[s]);
            h[s] = fmaf(dA, h[s], dt * dbs[t][DR + s] * xval);
            y = fmaf(h[s], dbs[t][DR + DS + s], y);
        }
        y = fmaf(xval, Dd, y);
        float zv = B2F(z_b[t * DI + d]);
        float sz = zv / (1.0f + __expf(-zv));
        xs_b[t * DI + d] = F2B(y * sz);
    }
}

// ---------------- out_proj MFMA (both dirs, flip-back) + residual ----------------
__global__ __launch_bounds__(256) void out_mfma(const bf16* __restrict__ yg,
                                                const float* __restrict__ Wf,
                                                const float* __restrict__ Wb,
                                                const float* __restrict__ x,
                                                float* __restrict__ out) {
    int b = blockIdx.x, n0 = blockIdx.y * 64;
    __shared__ __align__(16) char smem[18432];
    u16* A_lds = (u16*)smem;
    u16* B_lds = (u16*)(smem + 9216);
    float* tile = (float*)smem;
    int tid = threadIdx.x;
    int lane = tid & 63, wave = tid >> 6;
    int m_rel = lane & 15, quad = lane >> 4;
    int wrow0 = wave * 16;
    f32x4 acc[4];
    #pragma unroll
    for (int nt = 0; nt < 4; ++nt) acc[nt] = (f32x4){0.f, 0.f, 0.f, 0.f};

    int sr = tid >> 2, sc = (tid & 3) * 16;
    for (int dir = 0; dir < 2; ++dir) {
        const float* W = dir ? Wb : Wf;
        const u16* Ab = (const u16*)(yg + (size_t)(dir * NB + b) * MT * DI);
        int l = dir ? (MT - 1 - sr) : sr;    // logical row for physical sr
        for (int k0 = 0; k0 < DI; k0 += 64) {
            const uint4* asrc = (const uint4*)(Ab + (size_t)l * DI + k0 + sc);
            uint4* adst = (uint4*)(A_lds + sr * 72 + sc);
            adst[0] = asrc[0]; adst[1] = asrc[1];
            const float4* bsrc = (const float4*)(W + (size_t)(n0 + sr) * DI + k0 + sc);
            float4 b0 = bsrc[0], b1 = bsrc[1], b2 = bsrc[2], b3 = bsrc[3];
            uint4 p0 = { pack2bf(b0.x,b0.y), pack2bf(b0.z,b0.w), pack2bf(b1.x,b1.y), pack2bf(b1.z,b1.w) };
            uint4 p1 = { pack2bf(b2.x,b2.y), pack2bf(b2.z,b2.w), pack2bf(b3.x,b3.y), pack2bf(b3.z,b3.w) };
            uint4* bdst = (uint4*)(B_lds + sr * 72 + sc);
            bdst[0] = p0; bdst[1] = p1;
            __syncthreads();
            #pragma unroll
            for (int ks = 0; ks < 64; ks += 32) {
                short8 a = *(const short8*)(A_lds + (wrow0 + m_rel) * 72 + ks + quad * 8);
                #pragma unroll
                for (int nt = 0; nt < 4; ++nt) {
                    short8 bf = *(const short8*)(B_lds + (nt * 16 + m_rel) * 72 + ks + quad * 8);
                    acc[nt] = __builtin_amdgcn_mfma_f32_16x16x32_bf16(a, bf, acc[nt], 0, 0, 0);
                }
            }
            __syncthreads();
        }
    }
    #pragma unroll
    for (int nt = 0; nt < 4; ++nt)
        #pragma unroll
        for (int r = 0; r < 4; ++r)
            tile[(wrow0 + quad * 4 + r) * 65 + nt * 16 + m_rel] = acc[nt][r];
    __syncthreads();
    // coalesced fp32 write + residual
    int r = tid >> 2, c0 = (tid & 3) * 16;
    size_t obase = ((size_t)(b * MT + r)) * DM + n0 + c0;
    #pragma unroll
    for (int q = 0; q < 4; ++q) {
        float4 xv = *(const float4*)(x + obase + q * 4);
        float4 o;
        o.x = tile[r * 65 + c0 + q * 4 + 0] + xv.x;
        o.y = tile[r * 65 + c0 + q * 4 + 1] + xv.y;
        o.z = tile[r * 65 + c0 + q * 4 + 2] + xv.z;
        o.w = tile[r * 65 + c0 + q * 4 + 3] + xv.w;
        *(float4*)(out + obase + q * 4) = o;
    }
}

extern "C" void kernel_launch(void* const* d_in, const int* in_sizes, int n_in,
                              void* d_out, int out_size, void* d_ws, size_t ws_size,
                              hipStream_t stream) {
    float* out = (float*)d_out;
    static const int dictv[21] = {2097152,256,256,262144,262144,2048,2048,512,512,24576,24576,
                                  8192,8192,512,512,8192,8192,512,512,131072,131072};
    bool ok = (n_in == 21);
    if (ok) for (int i = 0; i < 21; ++i) if (in_sizes[i] != dictv[i]) { ok = false; break; }
    if (!ok) {
        fillcode_k<<<(out_size + 255) / 256, 256, 0, stream>>>(out, out_size, 4e9f);
        return;
    }
    const float* x     = (const float*)d_in[0];
    const float* lng   = (const float*)d_in[1];
    const float* lnb   = (const float*)d_in[2];
    const float* f_inw = (const float*)d_in[3];
    const float* b_inw = (const float*)d_in[4];
    const float* f_cw  = (const float*)d_in[5];
    const float* b_cw  = (const float*)d_in[6];
    const float* f_cb  = (const float*)d_in[7];
    const float* b_cb  = (const float*)d_in[8];
    const float* f_xpw = (const float*)d_in[9];
    const float* b_xpw = (const float*)d_in[10];
    const float* f_dtw = (const float*)d_in[11];
    const float* b_dtw = (const float*)d_in[12];
    const float* f_dtb = (const float*)d_in[13];
    const float* b_dtb = (const float*)d_in[14];
    const float* f_al  = (const float*)d_in[15];
    const float* b_al  = (const float*)d_in[16];
    const float* f_d   = (const float*)d_in[17];
    const float* b_d   = (const float*)d_in[18];
    const float* f_ow  = (const float*)d_in[19];
    const float* b_ow  = (const float*)d_in[20];

    bf16* xn   = (bf16*)d_ws;
    bf16* xs   = xn + (size_t)NTOK * DM;
    bf16* zb   = xs + (size_t)2 * NTOK * DI;
    float* dbc = (float*)((char*)d_ws + 37748736ull);

    ln_k<<<NTOK, 256, 0, stream>>>(x, lng, lnb, xn);
    {
        dim3 g(NB, (2 * DI) / 64, 2);
        inproj_conv_mfma<<<g, 256, 0, stream>>>(xn, f_inw, b_inw,
                                                f_cw, f_cb, b_cw, b_cb, xs, zb);
    }
    xproj_k<<<(2 * NTOK) / 64, 256, 0, stream>>>(xs, f_xpw, b_xpw, dbc);
    {
        dim3 g(2 * NB, DI / 256);
        scan_k<<<g, 256, 0, stream>>>(xs, zb, dbc,
                                      f_dtw, f_dtb, f_al, f_d,
                                      b_dtw, b_dtb, b_al, b_d);
    }
    {
        dim3 g(NB, DM / 64);
        out_mfma<<<g, 256, 0, stream>>>(xs, f_ow, b_ow, x, out);
    }
}

// Round 13
// 247.014 us; speedup vs baseline: 1.8902x; 1.2070x over previous
//
#include <hip/hip_runtime.h>
#include <hip/hip_bf16.h>

#define NB 128
#define MT 64
#define DM 256
#define DI 512
#define DS 16
#define DR 16
#define NTOK (NB*MT)   // 8192

using bf16 = __hip_bfloat16;
typedef unsigned short u16;
typedef __attribute__((ext_vector_type(8))) short short8;
typedef __attribute__((ext_vector_type(4))) float f32x4;

__device__ __forceinline__ float B2F(bf16 v) { return __bfloat162float(v); }
__device__ __forceinline__ bf16  F2B(float f) { return __float2bfloat16(f); }
__device__ __forceinline__ unsigned pack2bf(float lo, float hi) {
    unsigned a = __float_as_uint(lo), b = __float_as_uint(hi);
    a = (a + 0x7FFFu + ((a >> 16) & 1u)) >> 16;
    b = (b + 0x7FFFu + ((b >> 16) & 1u)) >> 16;
    return a | (b << 16);
}

// Inputs: fp32, dict-interleaved order. Output: fp32. Internal ws: bf16 (+fp32 dbc).
// ws: xn bf16 [0,2097152) | xs bf16 | zb bf16 | dbc f32 @ byte 37748736

__global__ void fillcode_k(float* out, int n, float code) {
    int i = blockIdx.x * 256 + threadIdx.x;
    if (i < n) out[i] = code;
}

// ---------------- LayerNorm (fp32 in, bf16 out) ----------------
__global__ __launch_bounds__(256) void ln_k(const float* __restrict__ x,
                                            const float* __restrict__ g,
                                            const float* __restrict__ bt,
                                            bf16* __restrict__ xn) {
    __shared__ float rs[256], rq[256];
    int tok = blockIdx.x, tid = threadIdx.x;
    float v = x[(size_t)tok * DM + tid];
    rs[tid] = v; rq[tid] = v * v;
    __syncthreads();
    for (int o = 128; o > 0; o >>= 1) {
        if (tid < o) { rs[tid] += rs[tid + o]; rq[tid] += rq[tid + o]; }
        __syncthreads();
    }
    float mu  = rs[0] * (1.0f / DM);
    float var = rq[0] * (1.0f / DM) - mu * mu;
    float inv = rsqrtf(fmaxf(var, 0.f) + 1e-5f);
    xn[(size_t)tok * DM + tid] = F2B((v - mu) * inv * g[tid] + bt[tid]);
}

// ---------------- in_proj MFMA GEMM (128x128 tile) + conv + SiLU ----------------
// block: 2 batches (128 time rows) x 128 channels. 4 waves 2x2, each 64x64.
__global__ __launch_bounds__(256) void inproj_mfma(
        const bf16* __restrict__ xn,
        const float* __restrict__ Wf, const float* __restrict__ Wb,
        const float* __restrict__ cwf, const float* __restrict__ cbf,
        const float* __restrict__ cwb, const float* __restrict__ cbb,
        bf16* __restrict__ xs, bf16* __restrict__ zb) {
    int bp = blockIdx.x;             // batch pair 0..63
    int n0 = blockIdx.y * 128;       // 0..896
    int dir = blockIdx.z;
    const float* W = dir ? Wb : Wf;
    __shared__ __align__(16) char smem[36864];
    u16* A_lds = (u16*)smem;                 // [128][72]
    u16* B_lds = (u16*)(smem + 18432);       // [128][72]
    float* tile = (float*)smem;              // [64][132] fp32 (aliased)
    int tid = threadIdx.x;
    int lane = tid & 63, wave = tid >> 6;
    int quad = lane >> 4, mrel = lane & 15;
    int row_base = (wave >> 1) * 64;         // 0 or 64 (batch within pair)
    int col_base = (wave & 1) * 64;
    f32x4 acc[4][4];
    #pragma unroll
    for (int i = 0; i < 4; ++i)
        #pragma unroll
        for (int j = 0; j < 4; ++j) acc[i][j] = (f32x4){0.f,0.f,0.f,0.f};

    const u16* Ap = (const u16*)(xn + (size_t)bp * 128 * DM);
    int srow = tid >> 1, scol = (tid & 1) * 32;   // 32 bf16 per thread
    for (int k0 = 0; k0 < DM; k0 += 64) {
        const uint4* asrc = (const uint4*)(Ap + (size_t)srow * DM + k0 + scol);
        uint4* adst = (uint4*)(A_lds + srow * 72 + scol);
        adst[0] = asrc[0]; adst[1] = asrc[1]; adst[2] = asrc[2]; adst[3] = asrc[3];  // 32 el (FIX)
        const float4* bsrc = (const float4*)(W + (size_t)(n0 + srow) * DM + k0 + scol);
        uint4* bdst = (uint4*)(B_lds + srow * 72 + scol);
        #pragma unroll
        for (int h = 0; h < 2; ++h) {
            float4 b0 = bsrc[h*4+0], b1 = bsrc[h*4+1], b2 = bsrc[h*4+2], b3 = bsrc[h*4+3];
            uint4 p; p.x = pack2bf(b0.x,b0.y); p.y = pack2bf(b0.z,b0.w);
            p.z = pack2bf(b1.x,b1.y); p.w = pack2bf(b1.z,b1.w);
            uint4 q; q.x = pack2bf(b2.x,b2.y); q.y = pack2bf(b2.z,b2.w);
            q.z = pack2bf(b3.x,b3.y); q.w = pack2bf(b3.z,b3.w);
            bdst[h*2+0] = p; bdst[h*2+1] = q;
        }
        __syncthreads();
        #pragma unroll
        for (int ks = 0; ks < 64; ks += 32) {
            short8 a[4], bfr[4];
            #pragma unroll
            for (int i = 0; i < 4; ++i)
                a[i] = *(const short8*)(A_lds + (row_base + i*16 + mrel) * 72 + ks + quad * 8);
            #pragma unroll
            for (int j = 0; j < 4; ++j)
                bfr[j] = *(const short8*)(B_lds + (col_base + j*16 + mrel) * 72 + ks + quad * 8);
            #pragma unroll
            for (int i = 0; i < 4; ++i)
                #pragma unroll
                for (int j = 0; j < 4; ++j)
                    acc[i][j] = __builtin_amdgcn_mfma_f32_16x16x32_bf16(a[i], bfr[j], acc[i][j], 0, 0, 0);
        }
        __syncthreads();
    }
    // two-phase epilogue: phase ph handles batch bp*2+ph (tile rows 0..63 local)
    int tx = tid & 31, ty = tid >> 5;    // cols c=tx+32j, rows l=ty*8..+7
    for (int ph = 0; ph < 2; ++ph) {
        if ((wave >> 1) == ph) {
            #pragma unroll
            for (int i = 0; i < 4; ++i)
                #pragma unroll
                for (int j = 0; j < 4; ++j)
                    #pragma unroll
                    for (int r = 0; r < 4; ++r)
                        tile[(i*16 + quad*4 + r) * 132 + col_base + j*16 + mrel] = acc[i][j][r];
        }
        __syncthreads();
        int b = bp * 2 + ph;
        size_t outbase = ((size_t)(dir * NB + b) * MT) * DI;
        if (n0 < DI) {
            const float* cw = dir ? cwb : cwf;
            const float* cb = dir ? cbb : cbf;
            #pragma unroll
            for (int i = 0; i < 8; ++i) {
                int l = ty * 8 + i;                      // logical time
                #pragma unroll
                for (int j = 0; j < 4; ++j) {
                    int c = tx + j * 32;
                    int d = n0 + c;
                    float a2 = cb[d];
                    #pragma unroll
                    for (int k = 0; k < 4; ++k) {
                        int jj = l - 3 + k;
                        if (jj >= 0) {
                            int p = dir ? (MT - 1 - jj) : jj;
                            a2 = fmaf(tile[p * 132 + c], cw[d * 4 + k], a2);
                        }
                    }
                    xs[outbase + (size_t)l * DI + d] = F2B(a2 / (1.0f + __expf(-a2)));
                }
            }
        } else {
            #pragma unroll
            for (int i = 0; i < 8; ++i) {
                int p = ty * 8 + i;                      // physical time
                int l = dir ? (MT - 1 - p) : p;
                #pragma unroll
                for (int j = 0; j < 4; ++j) {
                    int c = tx + j * 32;
                    zb[outbase + (size_t)l * DI + n0 - DI + c] = F2B(tile[p * 132 + c]);
                }
            }
        }
        __syncthreads();
    }
}

// ---------------- x_proj MFMA: dbc = xs @ W^T (M=64, N=48, K=512) ----------------
__global__ __launch_bounds__(256) void xproj_mfma(const bf16* __restrict__ xs,
                                                  const float* __restrict__ Wf,
                                                  const float* __restrict__ Wb,
                                                  float* __restrict__ dbc) {
    int bm = blockIdx.x;                 // 0..255
    int dir = bm >> 7;
    const float* W = dir ? Wb : Wf;
    __shared__ __align__(16) char smem[16128];
    u16* A_lds = (u16*)smem;             // [64][72]
    u16* B_lds = (u16*)(smem + 9216);    // [48][72]
    int m0 = bm * 64;
    int tid = threadIdx.x;
    int lane = tid & 63, wave = tid >> 6;
    int quad = lane >> 4, mrel = lane & 15;
    int wrow0 = wave * 16;
    f32x4 acc[3];
    #pragma unroll
    for (int j = 0; j < 3; ++j) acc[j] = (f32x4){0.f,0.f,0.f,0.f};
    int arow = tid >> 2, acol = (tid & 3) * 16;
    for (int k0 = 0; k0 < DI; k0 += 64) {
        const uint4* asrc = (const uint4*)((const u16*)xs + (size_t)(m0 + arow) * DI + k0 + acol);
        uint4* adst = (uint4*)(A_lds + arow * 72 + acol);
        adst[0] = asrc[0]; adst[1] = asrc[1];
        if (tid < 192) {
            int brow = tid >> 2, bcol = (tid & 3) * 16;
            const float4* bsrc = (const float4*)(W + (size_t)brow * DI + k0 + bcol);
            float4 b0 = bsrc[0], b1 = bsrc[1], b2 = bsrc[2], b3 = bsrc[3];
            uint4 p; p.x = pack2bf(b0.x,b0.y); p.y = pack2bf(b0.z,b0.w);
            p.z = pack2bf(b1.x,b1.y); p.w = pack2bf(b1.z,b1.w);
            uint4 q; q.x = pack2bf(b2.x,b2.y); q.y = pack2bf(b2.z,b2.w);
            q.z = pack2bf(b3.x,b3.y); q.w = pack2bf(b3.z,b3.w);
            uint4* bdst = (uint4*)(B_lds + brow * 72 + bcol);
            bdst[0] = p; bdst[1] = q;
        }
        __syncthreads();
        #pragma unroll
        for (int ks = 0; ks < 64; ks += 32) {
            short8 a = *(const short8*)(A_lds + (wrow0 + mrel) * 72 + ks + quad * 8);
            #pragma unroll
            for (int j = 0; j < 3; ++j) {
                short8 bf = *(const short8*)(B_lds + (j*16 + mrel) * 72 + ks + quad * 8);
                acc[j] = __builtin_amdgcn_mfma_f32_16x16x32_bf16(a, bf, acc[j], 0, 0, 0);
            }
        }
        __syncthreads();
    }
    #pragma unroll
    for (int j = 0; j < 3; ++j)
        #pragma unroll
        for (int r = 0; r < 4; ++r)
            dbc[(size_t)(m0 + wrow0 + quad*4 + r) * 48 + j*16 + mrel] = acc[j][r];
}

// ---------------- fused dt_proj + softplus + selective scan + gating ----------------
__global__ __launch_bounds__(256) void scan_k(bf16* __restrict__ xs,
                                              const bf16* __restrict__ zb,
                                              const float* __restrict__ dbc,
                                              const float* __restrict__ dtwf, const float* __restrict__ dtbf,
                                              const float* __restrict__ Alf,  const float* __restrict__ Df,
                                              const float* __restrict__ dtwb, const float* __restrict__ dtbb,
                                              const float* __restrict__ Alb,  const float* __restrict__ Db) {
    int db  = blockIdx.x;      // dir*128 + b
    int dir = db >> 7;
    int tid = threadIdx.x;
    int d   = blockIdx.y * 256 + tid;
    const float* dtw = dir ? dtwb : dtwf;
    const float* dtb = dir ? dtbb : dtbf;
    const float* Al  = dir ? Alb  : Alf;
    const float* Dv  = dir ? Db   : Df;
    __shared__ float dbs[MT][48];
    const float* dbc_b = dbc + (size_t)db * MT * 48;
    for (int idx = tid; idx < MT * 48; idx += 256) dbs[idx / 48][idx % 48] = dbc_b[idx];
    __syncthreads();
    float w[DR], A[DS], h[DS];
    #pragma unroll
    for (int r = 0; r < DR; ++r) w[r] = dtw[d * DR + r];
    #pragma unroll
    for (int s = 0; s < DS; ++s) { A[s] = -__expf(Al[d * DS + s]); h[s] = 0.f; }
    float bias = dtb[d], Dd = Dv[d];
    bf16* xs_b = xs + (size_t)db * MT * DI;
    const bf16* z_b = zb + (size_t)db * MT * DI;
    for (int t = 0; t < MT; ++t) {
        float xval = B2F(xs_b[t * DI + d]);
        float pre = bias;
        #pragma unroll
        for (int r = 0; r < DR; ++r) pre = fmaf(dbs[t][r], w[r], pre);
        float dt = (pre > 15.f) ? pre : __logf(1.0f + __expf(pre));
        float y = 0.f;
        #pragma unroll
        for (int s = 0; s < DS; ++s) {
            float dA = __expf(dt * A[s]);
            h[s] = fmaf(dA, h[s], dt * dbs[t][DR + s] * xval);
            y = fmaf(h[s], dbs[t][DR + DS + s], y);
        }
        y = fmaf(xval, Dd, y);
        float zv = B2F(z_b[t * DI + d]);
        float sz = zv / (1.0f + __expf(-zv));
        xs_b[t * DI + d] = F2B(y * sz);
    }
}

// ---------------- out_proj MFMA (M=64, N=128) + residual ----------------
__global__ __launch_bounds__(256) void out_mfma(const bf16* __restrict__ yg,
                                                const float* __restrict__ Wf,
                                                const float* __restrict__ Wb,
                                                const float* __restrict__ x,
                                                float* __restrict__ out) {
    int b = blockIdx.x, n0 = blockIdx.y * 128;
    __shared__ __align__(16) char smem[33792];
    u16* A_lds = (u16*)smem;               // [64][72]
    u16* B_lds = (u16*)(smem + 9216);      // [128][72]
    float* tile = (float*)smem;            // [64][132] (aliased)
    int tid = threadIdx.x;
    int lane = tid & 63, wave = tid >> 6;
    int quad = lane >> 4, mrel = lane & 15;
    int row_base = (wave >> 1) * 32;
    int col_base = (wave & 1) * 64;
    f32x4 acc[2][4];
    #pragma unroll
    for (int i = 0; i < 2; ++i)
        #pragma unroll
        for (int j = 0; j < 4; ++j) acc[i][j] = (f32x4){0.f,0.f,0.f,0.f};

    int arow = tid >> 2, acol = (tid & 3) * 16;
    int brow = tid >> 1, bcol = (tid & 1) * 32;
    for (int dir = 0; dir < 2; ++dir) {
        const float* W = dir ? Wb : Wf;
        const u16* Ap = (const u16*)(yg + (size_t)(dir * NB + b) * MT * DI);
        int l = dir ? (MT - 1 - arow) : arow;
        for (int k0 = 0; k0 < DI; k0 += 64) {
            const uint4* asrc = (const uint4*)(Ap + (size_t)l * DI + k0 + acol);
            uint4* adst = (uint4*)(A_lds + arow * 72 + acol);
            adst[0] = asrc[0]; adst[1] = asrc[1];
            const float4* bsrc = (const float4*)(W + (size_t)(n0 + brow) * DI + k0 + bcol);
            uint4* bdst = (uint4*)(B_lds + brow * 72 + bcol);
            #pragma unroll
            for (int hh = 0; hh < 2; ++hh) {
                float4 b0 = bsrc[hh*4+0], b1 = bsrc[hh*4+1], b2 = bsrc[hh*4+2], b3 = bsrc[hh*4+3];
                uint4 p; p.x = pack2bf(b0.x,b0.y); p.y = pack2bf(b0.z,b0.w);
                p.z = pack2bf(b1.x,b1.y); p.w = pack2bf(b1.z,b1.w);
                uint4 q; q.x = pack2bf(b2.x,b2.y); q.y = pack2bf(b2.z,b2.w);
                q.z = pack2bf(b3.x,b3.y); q.w = pack2bf(b3.z,b3.w);
                bdst[hh*2+0] = p; bdst[hh*2+1] = q;
            }
            __syncthreads();
            #pragma unroll
            for (int ks = 0; ks < 64; ks += 32) {
                short8 a[2], bfr[4];
                #pragma unroll
                for (int i = 0; i < 2; ++i)
                    a[i] = *(const short8*)(A_lds + (row_base + i*16 + mrel) * 72 + ks + quad * 8);
                #pragma unroll
                for (int j = 0; j < 4; ++j)
                    bfr[j] = *(const short8*)(B_lds + (col_base + j*16 + mrel) * 72 + ks + quad * 8);
                #pragma unroll
                for (int i = 0; i < 2; ++i)
                    #pragma unroll
                    for (int j = 0; j < 4; ++j)
                        acc[i][j] = __builtin_amdgcn_mfma_f32_16x16x32_bf16(a[i], bfr[j], acc[i][j], 0, 0, 0);
            }
            __syncthreads();
        }
    }
    #pragma unroll
    for (int i = 0; i < 2; ++i)
        #pragma unroll
        for (int j = 0; j < 4; ++j)
            #pragma unroll
            for (int r = 0; r < 4; ++r)
                tile[(row_base + i*16 + quad*4 + r) * 132 + col_base + j*16 + mrel] = acc[i][j][r];
    __syncthreads();
    int rr = tid >> 2, c0 = (tid & 3) * 32;
    size_t obase = ((size_t)(b * MT + rr)) * DM + n0 + c0;
    #pragma unroll
    for (int q = 0; q < 8; ++q) {
        float4 xv = *(const float4*)(x + obase + q * 4);
        float4 o;
        o.x = tile[rr * 132 + c0 + q*4 + 0] + xv.x;
        o.y = tile[rr * 132 + c0 + q*4 + 1] + xv.y;
        o.z = tile[rr * 132 + c0 + q*4 + 2] + xv.z;
        o.w = tile[rr * 132 + c0 + q*4 + 3] + xv.w;
        *(float4*)(out + obase + q * 4) = o;
    }
}

extern "C" void kernel_launch(void* const* d_in, const int* in_sizes, int n_in,
                              void* d_out, int out_size, void* d_ws, size_t ws_size,
                              hipStream_t stream) {
    float* out = (float*)d_out;
    static const int dictv[21] = {2097152,256,256,262144,262144,2048,2048,512,512,24576,24576,
                                  8192,8192,512,512,8192,8192,512,512,131072,131072};
    bool ok = (n_in == 21);
    if (ok) for (int i = 0; i < 21; ++i) if (in_sizes[i] != dictv[i]) { ok = false; break; }
    if (!ok) {
        fillcode_k<<<(out_size + 255) / 256, 256, 0, stream>>>(out, out_size, 4e9f);
        return;
    }
    const float* x     = (const float*)d_in[0];
    const float* lng   = (const float*)d_in[1];
    const float* lnb   = (const float*)d_in[2];
    const float* f_inw = (const float*)d_in[3];
    const float* b_inw = (const float*)d_in[4];
    const float* f_cw  = (const float*)d_in[5];
    const float* b_cw  = (const float*)d_in[6];
    const float* f_cb  = (const float*)d_in[7];
    const float* b_cb  = (const float*)d_in[8];
    const float* f_xpw = (const float*)d_in[9];
    const float* b_xpw = (const float*)d_in[10];
    const float* f_dtw = (const float*)d_in[11];
    const float* b_dtw = (const float*)d_in[12];
    const float* f_dtb = (const float*)d_in[13];
    const float* b_dtb = (const float*)d_in[14];
    const float* f_al  = (const float*)d_in[15];
    const float* b_al  = (const float*)d_in[16];
    const float* f_d   = (const float*)d_in[17];
    const float* b_d   = (const float*)d_in[18];
    const float* f_ow  = (const float*)d_in[19];
    const float* b_ow  = (const float*)d_in[20];

    bf16* xn   = (bf16*)d_ws;
    bf16* xs   = xn + (size_t)NTOK * DM;
    bf16* zb   = xs + (size_t)2 * NTOK * DI;
    float* dbc = (float*)((char*)d_ws + 37748736ull);

    ln_k<<<NTOK, 256, 0, stream>>>(x, lng, lnb, xn);
    {
        dim3 g(NB / 2, (2 * DI) / 128, 2);
        inproj_mfma<<<g, 256, 0, stream>>>(xn, f_inw, b_inw,
                                           f_cw, f_cb, b_cw, b_cb, xs, zb);
    }
    xproj_mfma<<<(2 * NTOK) / 64, 256, 0, stream>>>(xs, f_xpw, b_xpw, dbc);
    {
        dim3 g(2 * NB, DI / 256);
        scan_k<<<g, 256, 0, stream>>>(xs, zb, dbc,
                                      f_dtw, f_dtb, f_al, f_d,
                                      b_dtw, b_dtb, b_al, b_d);
    }
    {
        dim3 g(NB, DM / 128);
        out_mfma<<<g, 256, 0, stream>>>(xs, f_ow, b_ow, x, out);
    }
}